// Round 14
// baseline (64.775 us; speedup 1.0000x reference)
//
#include <hip/hip_runtime.h>
#include <math.h>

#define N 1024
#define IN_DIM 16
#define HID 64
#define MAXD 64

__device__ __forceinline__ float sigmoidf_(float x) {
    return 1.0f / (1.0f + __expf(-x));
}
// fast tanh via exp; ~1e-6 rel error, far below 1e-2 threshold
__device__ __forceinline__ float ftanh_(float x) {
    float e = __expf(2.0f * x);
    return 1.0f - 2.0f / (e + 1.0f);
}
// round-to-nearest-even fp32 -> bf16 bits
__device__ __forceinline__ unsigned rne16_(float f) {
    unsigned u = __float_as_uint(f);
    return (u + 0x7FFFu + ((u >> 16) & 1u)) >> 16;
}
__device__ __forceinline__ unsigned pack2_(float a, float b) {
    return rne16_(a) | (rne16_(b) << 16);
}
__device__ __forceinline__ float blo_(unsigned u) { return __uint_as_float(u << 16); }
__device__ __forceinline__ float bhi_(unsigned u) { return __uint_as_float(u & 0xFFFF0000u); }

// padded LDS word counts: [row][k2] with stride 33 => conflict-free reads
#define IH_WORDS  (192 * 33)
#define HH_WORDS  (192 * 33)
#define MSG_WORDS (64 * 33)

// GRU for one lane (lane = output index j); weights in padded bf16 LDS
__device__ __forceinline__ float gru_lane(const unsigned* swih, const unsigned* swhh,
                                          const float* mvec, const float* hvec,
                                          const float* b_ih, const float* b_hh,
                                          int lane, float hu) {
    float accR  = b_ih[lane]        + b_hh[lane];
    float accZ  = b_ih[64 + lane]   + b_hh[64 + lane];
    float accNi = b_ih[128 + lane];
    float accNh = b_hh[128 + lane];
    const float2* m2 = (const float2*)mvec;
    const float2* h2 = (const float2*)hvec;
#pragma unroll
    for (int k2 = 0; k2 < 32; ++k2) {
        float2 mv = m2[k2];
        float2 hv = h2[k2];
        unsigned wiR = swih[lane * 33 + k2];
        unsigned wiZ = swih[(64 + lane) * 33 + k2];
        unsigned wiN = swih[(128 + lane) * 33 + k2];
        unsigned whR = swhh[lane * 33 + k2];
        unsigned whZ = swhh[(64 + lane) * 33 + k2];
        unsigned whN = swhh[(128 + lane) * 33 + k2];
        accR  += mv.x * blo_(wiR) + mv.y * bhi_(wiR)
               + hv.x * blo_(whR) + hv.y * bhi_(whR);
        accZ  += mv.x * blo_(wiZ) + mv.y * bhi_(wiZ)
               + hv.x * blo_(whZ) + hv.y * bhi_(whZ);
        accNi += mv.x * blo_(wiN) + mv.y * bhi_(wiN);
        accNh += hv.x * blo_(whN) + hv.y * bhi_(whN);
    }
    float r = sigmoidf_(accR);
    float z = sigmoidf_(accZ);
    float n = ftanh_(accNi + r * accNh);
    return (1.0f - z) * n + z * hu;
}

__device__ __forceinline__ float proj_lane(const unsigned* swmsg, const float* hvec,
                                           const float* b_msg, int lane) {
    float pa = b_msg[lane];
    const float2* h2 = (const float2*)hvec;
#pragma unroll
    for (int k2 = 0; k2 < 32; ++k2) {
        float2 hh = h2[k2];
        unsigned wm = swmsg[lane * 33 + k2];
        pa += hh.x * blo_(wm) + hh.y * bhi_(wm);
    }
    return pa;
}

// ==== fused1 (r10-proven): CSR + encoder + step1 (proj0 recomputed in-wave) ====
// 256 blocks x 512 threads; 4 nodes/block, 2 waves/node (neighbor halves)
__global__ void __launch_bounds__(512) fused1_kernel(
    const float* __restrict__ A, const float* __restrict__ E,
    const float* __restrict__ X,
    const float* __restrict__ W_enc, const float* __restrict__ b_enc,
    const float* __restrict__ W_msg, const float* __restrict__ b_msg,
    const float* __restrict__ W_ih, const float* __restrict__ W_hh,
    const float* __restrict__ b_ih, const float* __restrict__ b_hh,
    const float* __restrict__ W_r1,
    int* __restrict__ nbr, float* __restrict__ ev, float* __restrict__ deg,
    float* __restrict__ h1, float* __restrict__ p1, float* __restrict__ Wr1T)
{
    int tid = threadIdx.x;
    int wave = tid >> 6;         // 0..7
    int lane = tid & 63;
    int slot = wave & 3;         // node slot in block
    int half = wave >> 2;        // neighbor half
    int u = blockIdx.x * 4 + slot;

    __shared__ unsigned swih[IH_WORDS];
    __shared__ unsigned swhh[HH_WORDS];
    __shared__ unsigned swmsg[MSG_WORDS];
    __shared__ float swenc[64 * 17];
    __shared__ int   snbr[4][MAXD];
    __shared__ float sev[4][MAXD];
    __shared__ float sdeg[4];
    __shared__ float hbuf[8][HID];
    __shared__ float ssum[4][2][HID];
    __shared__ float sm[4][2][HID];

    // ---- pack GRU weights bf16 -> padded LDS (coalesced fp32 reads) ----
    for (int idx = tid; idx < 6144; idx += 512) {
        int row = idx >> 5, k2 = idx & 31;
        float2 wi = *(const float2*)&W_ih[row * 64 + 2 * k2];
        swih[row * 33 + k2] = pack2_(wi.x, wi.y);
        float2 wh = *(const float2*)&W_hh[row * 64 + 2 * k2];
        swhh[row * 33 + k2] = pack2_(wh.x, wh.y);
    }
    for (int idx = tid; idx < 2048; idx += 512) {      // W_msg rows stride 65 (odd)
        int row = idx >> 5, k2 = idx & 31;
        swmsg[row * 33 + k2] = pack2_(W_msg[row * 65 + 2 * k2],
                                      W_msg[row * 65 + 2 * k2 + 1]);
    }
    for (int idx = tid; idx < 1024; idx += 512) {      // encoder fp32 [64][17]
        int row = idx >> 4, k = idx & 15;
        swenc[row * 17 + k] = W_enc[row * 16 + k];
    }
    // Wr1T transpose (blocks 0..15 cover 8192 elements)
    {
        int gid = blockIdx.x * 512 + tid;
        if (gid < 8192) {
            int j = gid >> 7, k = gid & 127;
            Wr1T[k * 64 + j] = W_r1[gid];
        }
    }

    // ---- CSR build (waves 0-3, in-wave ballots) ----
    if (half == 0) {
        snbr[slot][lane] = 0;
        sev[slot][lane] = 0.0f;
        int count = 0;
        for (int c = 0; c < 16; ++c) {
            int v = c * 64 + lane;
            float a = A[u * N + v];
            bool has = (a > 0.0f);
            unsigned long long b = __ballot(has);
            if (has) {
                int s = count + __popcll(b & ((1ull << lane) - 1ull));
                if (s < MAXD) { snbr[slot][s] = v; sev[slot][s] = E[u * N + v]; }
            }
            count += __popcll(b);
        }
        if (lane == 0) { sdeg[slot] = (float)count; deg[u] = (float)count; }
        // persist CSR for later kernels (full 64-entry rows, zero-filled)
        nbr[u * MAXD + lane] = snbr[slot][lane];
        ev[u * MAXD + lane] = sev[slot][lane];
    }
    __syncthreads();   // sw*/swenc staged, CSR + sdeg ready

    // ---- gather with proj0 recompute; this wave handles i = half, half+2, ... ----
    float d = sdeg[slot];
    int dn = min((int)d, MAXD);
    float we = W_msg[lane * 65 + 64];
    float sum = 0.0f;
    for (int i = half; i < dn; i += 2) {
        int v = snbr[slot][i];       // broadcast
        float e = sev[slot][i];      // broadcast
        // h0[v] = tanh(X[v]·Wenc + b_enc)
        float a2 = b_enc[lane];
#pragma unroll
        for (int k = 0; k < IN_DIM; ++k)
            a2 += X[v * IN_DIM + k] * swenc[lane * 17 + k];
        float hv = ftanh_(a2);
        hbuf[wave][lane] = hv;       // in-wave LDS (DS ops ordered per wave)
        float pa = proj_lane(swmsg, hbuf[wave], b_msg, lane);
        sum += ftanh_(pa + e * we);
    }
    ssum[slot][half][lane] = sum;
    __syncthreads();

    // ---- GRU + proj(h1) (waves 0-3) ----
    if (half == 0) {
        float s = ssum[slot][0][lane] + ssum[slot][1][lane];
        float msg = (dn > 0) ? (s / d) : 0.0f;
        // h0[u]
        float a0 = b_enc[lane];
#pragma unroll
        for (int k = 0; k < IN_DIM; ++k)
            a0 += X[u * IN_DIM + k] * swenc[lane * 17 + k];
        float hu = ftanh_(a0);
        sm[slot][0][lane] = msg;
        sm[slot][1][lane] = hu;
        float hnew = gru_lane(swih, swhh, sm[slot][0], sm[slot][1],
                              b_ih, b_hh, lane, hu);
        h1[u * HID + lane] = hnew;
        sm[slot][0][lane] = hnew;    // same-wave reuse
        p1[u * HID + lane] = proj_lane(swmsg, sm[slot][0], b_msg, lane);
    }
}

// ==== step2: wide (256 blocks x 512 threads), inline-packed LDS weights ====
__global__ void __launch_bounds__(512) step2_kernel(
    const float* __restrict__ W_msg, const float* __restrict__ b_msg,
    const float* __restrict__ W_ih, const float* __restrict__ W_hh,
    const float* __restrict__ b_ih, const float* __restrict__ b_hh,
    const int* __restrict__ nbr, const float* __restrict__ ev,
    const float* __restrict__ deg,
    const float* __restrict__ h1, const float* __restrict__ p1,
    float* __restrict__ h2, float* __restrict__ p2)
{
    int tid = threadIdx.x;
    int wave = tid >> 6;         // 0..7
    int lane = tid & 63;
    int slot = wave & 3;
    int half = wave >> 2;
    int u = blockIdx.x * 4 + slot;

    __shared__ unsigned swih[IH_WORDS];
    __shared__ unsigned swhh[HH_WORDS];
    __shared__ unsigned swmsg[MSG_WORDS];
    __shared__ float ssum[4][2][HID];
    __shared__ float sm[4][2][HID];

    for (int idx = tid; idx < 6144; idx += 512) {
        int row = idx >> 5, k2 = idx & 31;
        float2 wi = *(const float2*)&W_ih[row * 64 + 2 * k2];
        swih[row * 33 + k2] = pack2_(wi.x, wi.y);
        float2 wh = *(const float2*)&W_hh[row * 64 + 2 * k2];
        swhh[row * 33 + k2] = pack2_(wh.x, wh.y);
    }
    for (int idx = tid; idx < 2048; idx += 512) {
        int row = idx >> 5, k2 = idx & 31;
        swmsg[row * 33 + k2] = pack2_(W_msg[row * 65 + 2 * k2],
                                      W_msg[row * 65 + 2 * k2 + 1]);
    }

    // ---- gather: lane i holds neighbor i; shfl-broadcast, p1 rows coalesced ----
    float we = W_msg[lane * 65 + 64];
    float d = deg[u];
    int dn = min((int)d, MAXD);
    int   rv = nbr[u * MAXD + lane];
    float re = ev[u * MAXD + lane];
    float sum = 0.0f;
    for (int i = half; i < dn; i += 2) {
        int v = __shfl(rv, i);
        float e = __shfl(re, i);
        sum += ftanh_(p1[v * HID + lane] + e * we);
    }
    ssum[slot][half][lane] = sum;
    __syncthreads();   // ssum ready AND weights staged

    // ---- GRU + proj(h2) (waves 0-3) ----
    if (half == 0) {
        float s = ssum[slot][0][lane] + ssum[slot][1][lane];
        float msg = (dn > 0) ? (s / d) : 0.0f;
        float hu = h1[u * HID + lane];
        sm[slot][0][lane] = msg;
        sm[slot][1][lane] = hu;
        float hnew = gru_lane(swih, swhh, sm[slot][0], sm[slot][1],
                              b_ih, b_hh, lane, hu);
        h2[u * HID + lane] = hnew;
        sm[slot][0][lane] = hnew;    // same-wave reuse
        p2[u * HID + lane] = proj_lane(swmsg, sm[slot][0], b_msg, lane);
    }
}

// ==== final: 1 block x 256. wave0 -> h3[src], wave1 -> h3[tgt], readout ====
__global__ void __launch_bounds__(256) final_kernel(
    const float* __restrict__ W_msg, const float* __restrict__ b_msg,
    const float* __restrict__ W_ih, const float* __restrict__ W_hh,
    const float* __restrict__ b_ih, const float* __restrict__ b_hh,
    const float* __restrict__ Wr1T, const float* __restrict__ b_r1,
    const float* __restrict__ W_r2, const float* __restrict__ b_r2,
    const int* __restrict__ src, const int* __restrict__ tgt,
    const int* __restrict__ nbr, const float* __restrict__ ev,
    const float* __restrict__ deg,
    const float* __restrict__ h2, const float* __restrict__ p2,
    float* __restrict__ out)
{
    int tid = threadIdx.x;
    int wave = tid >> 6;       // 0..3
    int lane = tid & 63;

    __shared__ unsigned swih[IH_WORDS];
    __shared__ unsigned swhh[HH_WORDS];
    __shared__ float smm[2][2][HID];
    __shared__ float smh3[2][HID];

    for (int idx = tid; idx < 6144; idx += 256) {
        int row = idx >> 5, k2 = idx & 31;
        float2 wi = *(const float2*)&W_ih[row * 64 + 2 * k2];
        swih[row * 33 + k2] = pack2_(wi.x, wi.y);
        float2 wh = *(const float2*)&W_hh[row * 64 + 2 * k2];
        swhh[row * 33 + k2] = pack2_(wh.x, wh.y);
    }

    if (wave < 2) {
        int u = (wave == 0) ? src[0] : tgt[0];
        float we = W_msg[lane * 65 + 64];
        float d = deg[u];
        int dn = min((int)d, MAXD);
        int   rv = nbr[u * MAXD + lane];
        float re = ev[u * MAXD + lane];
        float sum = 0.0f;
        for (int i = 0; i < dn; ++i) {
            int v = __shfl(rv, i);
            float e = __shfl(re, i);
            sum += ftanh_(p2[v * HID + lane] + e * we);
        }
        float msg = (dn > 0) ? (sum / d) : 0.0f;
        smm[wave][0][lane] = msg;
        smm[wave][1][lane] = h2[u * HID + lane];
    }
    __syncthreads();   // weights staged AND smm ready

    if (wave < 2) {
        float hu = smm[wave][1][lane];
        smh3[wave][lane] = gru_lane(swih, swhh, smm[wave][0], smm[wave][1],
                                    b_ih, b_hh, lane, hu);
    }
    __syncthreads();

    if (wave == 0) {
        float acc = b_r1[lane];
#pragma unroll 8
        for (int k = 0; k < HID; ++k)
            acc += smh3[0][k] * Wr1T[k * 64 + lane];
#pragma unroll 8
        for (int k = 0; k < HID; ++k)
            acc += smh3[1][k] * Wr1T[(HID + k) * 64 + lane];
        float hid = fmaxf(acc, 0.0f);
        float p = hid * W_r2[lane];
#pragma unroll
        for (int off = 32; off > 0; off >>= 1)
            p += __shfl_down(p, off);
        if (lane == 0) out[0] = sigmoidf_(p + b_r2[0]);
    }
}

extern "C" void kernel_launch(void* const* d_in, const int* in_sizes, int n_in,
                              void* d_out, int out_size, void* d_ws, size_t ws_size,
                              hipStream_t stream) {
    const float* A     = (const float*)d_in[0];
    const float* E     = (const float*)d_in[1];
    const float* X     = (const float*)d_in[2];
    const float* W_enc = (const float*)d_in[3];
    const float* b_enc = (const float*)d_in[4];
    const float* W_msg = (const float*)d_in[5];
    const float* b_msg = (const float*)d_in[6];
    const float* W_ih  = (const float*)d_in[7];
    const float* W_hh  = (const float*)d_in[8];
    const float* b_ih  = (const float*)d_in[9];
    const float* b_hh  = (const float*)d_in[10];
    const float* W_r1  = (const float*)d_in[11];
    const float* b_r1  = (const float*)d_in[12];
    const float* W_r2  = (const float*)d_in[13];
    const float* b_r2  = (const float*)d_in[14];
    const int*   src   = (const int*)d_in[15];
    const int*   tgt   = (const int*)d_in[16];
    // steps fixed at 3 in the reference: step1 in fused1, step2 wide, step3 in final.

    // workspace layout
    float* ws   = (float*)d_ws;
    float* h1   = ws;                      // N*HID
    float* p1   = h1 + N * HID;            // N*HID
    float* h2   = p1 + N * HID;            // N*HID
    float* p2   = h2 + N * HID;            // N*HID
    float* deg  = p2 + N * HID;            // N
    float* ev   = deg + N;                 // N*MAXD
    int*   nbr  = (int*)(ev + N * MAXD);   // N*MAXD ints
    float* Wr1T = (float*)(nbr + N * MAXD); // [128][64]

    fused1_kernel<<<256, 512, 0, stream>>>(A, E, X, W_enc, b_enc, W_msg, b_msg,
                                           W_ih, W_hh, b_ih, b_hh, W_r1,
                                           nbr, ev, deg, h1, p1, Wr1T);

    step2_kernel<<<256, 512, 0, stream>>>(W_msg, b_msg, W_ih, W_hh, b_ih, b_hh,
                                          nbr, ev, deg, h1, p1, h2, p2);

    final_kernel<<<1, 256, 0, stream>>>(W_msg, b_msg, W_ih, W_hh, b_ih, b_hh,
                                        Wr1T, b_r1, W_r2, b_r2, src, tgt,
                                        nbr, ev, deg, h2, p2, (float*)d_out);
}

// Round 15
// 45.630 us; speedup vs baseline: 1.4196x; 1.4196x over previous
//
#include <hip/hip_runtime.h>
#include <math.h>

#define N 1024
#define IN_DIM 16
#define HID 64
#define MAXD 64

__device__ __forceinline__ float sigmoidf_(float x) {
    return 1.0f / (1.0f + __expf(-x));
}
// fast tanh via exp; ~1e-6 rel error, far below 1e-2 threshold
__device__ __forceinline__ float ftanh_(float x) {
    float e = __expf(2.0f * x);
    return 1.0f - 2.0f / (e + 1.0f);
}
// round-to-nearest-even fp32 -> bf16 bits
__device__ __forceinline__ unsigned rne16_(float f) {
    unsigned u = __float_as_uint(f);
    return (u + 0x7FFFu + ((u >> 16) & 1u)) >> 16;
}
__device__ __forceinline__ float blo_(unsigned u) {  // low bf16 -> float
    return __uint_as_float(u << 16);
}
__device__ __forceinline__ float bhi_(unsigned u) {  // high bf16 -> float
    return __uint_as_float(u & 0xFFFF0000u);
}

// packed weight word counts
#define WIH_W 6144   // [k2=32][row=192] two bf16 (k=2k2, 2k2+1) per word
#define WHH_W 6144
#define WMSG_W 2048  // [k2=32][j=64]
#define WPACK_W (WIH_W + WHH_W + WMSG_W)  // 14336 u32 = 56 KB

// ---- fused init (r8-proven):
//   blocks [0,256)    : encoder + proj0 (4 nodes/block)
//   blocks [256,1280) : CSR build (1 block/row)
//   blocks [1280,1368): bf16 weight packing + Wr1T transpose
__global__ void init_kernel(const float* __restrict__ X,
                            const float* __restrict__ W_enc,
                            const float* __restrict__ b_enc,
                            const float* __restrict__ W_msg,
                            const float* __restrict__ b_msg,
                            const float* __restrict__ W_ih,
                            const float* __restrict__ W_hh,
                            const float* __restrict__ W_r1,
                            const float* __restrict__ A,
                            const float* __restrict__ E,
                            float* __restrict__ h,
                            float* __restrict__ proj,
                            int* __restrict__ nbr,
                            float* __restrict__ ev,
                            float* __restrict__ deg,
                            unsigned* __restrict__ Wpack,
                            float* __restrict__ Wr1T) {
    int bid = blockIdx.x;
    int tid = threadIdx.x;
    int wave = tid >> 6;
    int lane = tid & 63;

    if (bid < 256) {
        // ---- encoder + proj0 ----
        int u = bid * 4 + wave;
        __shared__ float sh[4][HID];
        float acc = b_enc[lane];
#pragma unroll
        for (int k = 0; k < IN_DIM; ++k)
            acc += X[u * IN_DIM + k] * W_enc[lane * IN_DIM + k];
        float hv = tanhf(acc);
        h[u * HID + lane] = hv;
        sh[wave][lane] = hv;
        __syncthreads();
        float pacc = b_msg[lane];
        const float4* h4 = (const float4*)sh[wave];
#pragma unroll
        for (int k4 = 0; k4 < HID / 4; ++k4) {
            float4 hh = h4[k4];
            const float* w = &W_msg[lane * (HID + 1) + k4 * 4];
            pacc += hh.x * w[0] + hh.y * w[1] + hh.z * w[2] + hh.w * w[3];
        }
        proj[u * HID + lane] = pacc;
    } else if (bid < 1280) {
        // ---- CSR build: one 256-thread block per row u ----
        int u = bid - 256;
        __shared__ unsigned long long balls[16];
        __shared__ int base[16];
        float evr[4];
        bool has[4];
#pragma unroll
        for (int ci = 0; ci < 4; ++ci) {
            int chunk = wave * 4 + ci;
            int v = chunk * 64 + lane;
            float a = A[u * N + v];
            bool hs = (a > 0.0f);
            has[ci] = hs;
            evr[ci] = E[u * N + v];
            unsigned long long b = __ballot(hs);
            if (lane == 0) balls[chunk] = b;
        }
        __syncthreads();
        if (tid == 0) {
            int s = 0;
#pragma unroll
            for (int c = 0; c < 16; ++c) {
                base[c] = s;
                s += __popcll(balls[c]);
            }
            deg[u] = (float)s;
        }
        __syncthreads();
#pragma unroll
        for (int ci = 0; ci < 4; ++ci) {
            int chunk = wave * 4 + ci;
            if (has[ci]) {
                unsigned long long b = balls[chunk];
                int slot = base[chunk] + __popcll(b & ((1ull << lane) - 1ull));
                if (slot < MAXD) {
                    nbr[u * MAXD + slot] = chunk * 64 + lane;
                    ev[u * MAXD + slot] = evr[ci];
                }
            }
        }
    } else {
        // ---- bf16 weight packing: one u32 per thread ----
        int t = (bid - 1280) * 256 + tid;
        if (t < WIH_W) {                       // WihTp[k2*192+row]
            int k2 = t / 192, row = t % 192;
            int k = 2 * k2;
            unsigned lo = rne16_(W_ih[row * 64 + k]);
            unsigned hi = rne16_(W_ih[row * 64 + k + 1]);
            Wpack[t] = lo | (hi << 16);
        } else if (t < WIH_W + WHH_W) {        // WhhTp
            int t0 = t - WIH_W;
            int k2 = t0 / 192, row = t0 % 192;
            int k = 2 * k2;
            unsigned lo = rne16_(W_hh[row * 64 + k]);
            unsigned hi = rne16_(W_hh[row * 64 + k + 1]);
            Wpack[t] = lo | (hi << 16);
        } else if (t < WPACK_W) {              // WmsgTp[k2*64+j]
            int t0 = t - WIH_W - WHH_W;
            int k2 = t0 >> 6, j = t0 & 63;
            int k = 2 * k2;
            unsigned lo = rne16_(W_msg[j * (HID + 1) + k]);
            unsigned hi = rne16_(W_msg[j * (HID + 1) + k + 1]);
            Wpack[t] = lo | (hi << 16);
        } else if (t < WPACK_W + 8192) {       // Wr1T[k*64+j] = W_r1[j*128+k], fp32
            int t0 = t - WPACK_W;
            int j = t0 >> 7, k = t0 & 127;
            Wr1T[k * 64 + j] = W_r1[t0];
        }
    }
}

// ---- fused step: LDS-staged bf16 weights; msg-gather + GRU + proj(h_new) ----
//      512 threads / 8 nodes per block: halves the staging iterations (7 vs 14)
__global__ void step_kernel(const float* __restrict__ proj,      // proj of h_in
                            const float* __restrict__ W_msg,     // only w_e col
                            const float* __restrict__ b_msg,
                            const float* __restrict__ hin,
                            const int* __restrict__ nbr,
                            const float* __restrict__ ev,
                            const float* __restrict__ deg,
                            const unsigned* __restrict__ Wpack,  // 14336 u32
                            const float* __restrict__ b_ih,
                            const float* __restrict__ b_hh,
                            float* __restrict__ hout,
                            float* __restrict__ projout,
                            int do_proj) {
    int tid = threadIdx.x;
    int wave = tid >> 6;     // 8 waves / block, wave = node slot
    int lane = tid & 63;     // lane = hidden index
    int u = blockIdx.x * 8 + wave;

    __shared__ unsigned sw[WPACK_W];   // 56 KB packed weights
    __shared__ float sm[8][2][HID];    // [0]=msgs (later h_new), [1]=h_u

    // stage weights block-wide (uint4 = 16B chunks; 7 iters @ 512 threads)
    {
        const uint4* gsrc = (const uint4*)Wpack;
        uint4* dst = (uint4*)sw;
#pragma unroll
        for (int c = 0; c < WPACK_W / 4 / 512; ++c)
            dst[c * 512 + tid] = gsrc[c * 512 + tid];
    }

    // ---- message gather (independent of sw) ----
    float we = W_msg[lane * (HID + 1) + HID];
    float d = deg[u];
    int dn = (int)d;
    float hu = hin[u * HID + lane];
    float sum = 0.0f;
    int i = 0;
    for (; i + 8 <= dn; i += 8) {
        int4 na = *(const int4*)&nbr[u * MAXD + i];
        int4 nb = *(const int4*)&nbr[u * MAXD + i + 4];
        float4 ea = *(const float4*)&ev[u * MAXD + i];
        float4 eb = *(const float4*)&ev[u * MAXD + i + 4];
        float q0 = proj[na.x * HID + lane];
        float q1 = proj[na.y * HID + lane];
        float q2 = proj[na.z * HID + lane];
        float q3 = proj[na.w * HID + lane];
        float q4 = proj[nb.x * HID + lane];
        float q5 = proj[nb.y * HID + lane];
        float q6 = proj[nb.z * HID + lane];
        float q7 = proj[nb.w * HID + lane];
        sum += ftanh_(q0 + ea.x * we) + ftanh_(q1 + ea.y * we)
             + ftanh_(q2 + ea.z * we) + ftanh_(q3 + ea.w * we);
        sum += ftanh_(q4 + eb.x * we) + ftanh_(q5 + eb.y * we)
             + ftanh_(q6 + eb.z * we) + ftanh_(q7 + eb.w * we);
    }
    for (; i + 4 <= dn; i += 4) {
        int4 nb = *(const int4*)&nbr[u * MAXD + i];
        float4 e4 = *(const float4*)&ev[u * MAXD + i];
        float q0 = proj[nb.x * HID + lane];
        float q1 = proj[nb.y * HID + lane];
        float q2 = proj[nb.z * HID + lane];
        float q3 = proj[nb.w * HID + lane];
        sum += ftanh_(q0 + e4.x * we) + ftanh_(q1 + e4.y * we)
             + ftanh_(q2 + e4.z * we) + ftanh_(q3 + e4.w * we);
    }
    for (; i < dn; ++i)
        sum += ftanh_(proj[nbr[u * MAXD + i] * HID + lane]
                      + ev[u * MAXD + i] * we);
    float msg = (dn > 0) ? (sum / d) : 0.0f;

    sm[wave][0][lane] = msg;
    sm[wave][1][lane] = hu;
    __syncthreads();   // sm ready AND sw staged

    // ---- GRU from LDS bf16 weights: lane j = output j ----
    const unsigned* swih = sw;
    const unsigned* swhh = sw + WIH_W;
    float accR  = b_ih[lane]       + b_hh[lane];
    float accZ  = b_ih[64 + lane]  + b_hh[64 + lane];
    float accNi = b_ih[128 + lane];
    float accNh = b_hh[128 + lane];
    const float2* m2 = (const float2*)sm[wave][0];
    const float2* h2 = (const float2*)sm[wave][1];
#pragma unroll
    for (int k2 = 0; k2 < 32; ++k2) {
        float2 mv = m2[k2];
        float2 hv = h2[k2];
        unsigned wiR = swih[k2 * 192 + lane];
        unsigned wiZ = swih[k2 * 192 + 64 + lane];
        unsigned wiN = swih[k2 * 192 + 128 + lane];
        unsigned whR = swhh[k2 * 192 + lane];
        unsigned whZ = swhh[k2 * 192 + 64 + lane];
        unsigned whN = swhh[k2 * 192 + 128 + lane];
        accR  += mv.x * blo_(wiR) + mv.y * bhi_(wiR)
               + hv.x * blo_(whR) + hv.y * bhi_(whR);
        accZ  += mv.x * blo_(wiZ) + mv.y * bhi_(wiZ)
               + hv.x * blo_(whZ) + hv.y * bhi_(whZ);
        accNi += mv.x * blo_(wiN) + mv.y * bhi_(wiN);
        accNh += hv.x * blo_(whN) + hv.y * bhi_(whN);
    }
    float r = sigmoidf_(accR);
    float z = sigmoidf_(accZ);
    float n = ftanh_(accNi + r * accNh);
    float hnew = (1.0f - z) * n + z * hu;
    hout[u * HID + lane] = hnew;

    if (do_proj) {
        __syncthreads();             // all waves done reading sm
        sm[wave][0][lane] = hnew;
        __syncthreads();
        const unsigned* swmsg = sw + WIH_W + WHH_W;
        float pacc = b_msg[lane];
        const float2* n2 = (const float2*)sm[wave][0];
#pragma unroll
        for (int k2 = 0; k2 < 32; ++k2) {
            float2 hh = n2[k2];
            unsigned wm = swmsg[k2 * 64 + lane];
            pacc += hh.x * blo_(wm) + hh.y * bhi_(wm);
        }
        projout[u * HID + lane] = pacc;
    }
}

// ---- readout: scalar sigmoid(MLP(cat(h[s], h[t]))), coalesced W_r1T ----
__global__ void readout_kernel(const float* __restrict__ h,
                               const float* __restrict__ Wr1T,   // [128][64]
                               const float* __restrict__ b_r1,
                               const float* __restrict__ W_r2,
                               const float* __restrict__ b_r2,
                               const int* __restrict__ src,
                               const int* __restrict__ tgt,
                               float* __restrict__ out) {
    int lane = threadIdx.x;  // 64 threads, 1 wave
    int sI = src[0];
    int tI = tgt[0];
    float acc = b_r1[lane];
#pragma unroll 8
    for (int k = 0; k < HID; ++k)
        acc += h[sI * HID + k] * Wr1T[k * 64 + lane];
#pragma unroll 8
    for (int k = 0; k < HID; ++k)
        acc += h[tI * HID + k] * Wr1T[(HID + k) * 64 + lane];
    float hid = fmaxf(acc, 0.0f);
    float p = hid * W_r2[lane];
#pragma unroll
    for (int off = 32; off > 0; off >>= 1)
        p += __shfl_down(p, off);
    if (lane == 0) out[0] = sigmoidf_(p + b_r2[0]);
}

extern "C" void kernel_launch(void* const* d_in, const int* in_sizes, int n_in,
                              void* d_out, int out_size, void* d_ws, size_t ws_size,
                              hipStream_t stream) {
    const float* A     = (const float*)d_in[0];
    const float* E     = (const float*)d_in[1];
    const float* X     = (const float*)d_in[2];
    const float* W_enc = (const float*)d_in[3];
    const float* b_enc = (const float*)d_in[4];
    const float* W_msg = (const float*)d_in[5];
    const float* b_msg = (const float*)d_in[6];
    const float* W_ih  = (const float*)d_in[7];
    const float* W_hh  = (const float*)d_in[8];
    const float* b_ih  = (const float*)d_in[9];
    const float* b_hh  = (const float*)d_in[10];
    const float* W_r1  = (const float*)d_in[11];
    const float* b_r1  = (const float*)d_in[12];
    const float* W_r2  = (const float*)d_in[13];
    const float* b_r2  = (const float*)d_in[14];
    const int*   src   = (const int*)d_in[15];
    const int*   tgt   = (const int*)d_in[16];
    // steps fixed at 3 in the reference.

    // workspace layout
    float* ws    = (float*)d_ws;
    float* h0    = ws;                       // N*HID
    float* h1    = h0 + N * HID;             // N*HID
    float* p0    = h1 + N * HID;             // N*HID
    float* p1    = p0 + N * HID;             // N*HID
    float* deg   = p1 + N * HID;             // N
    float* ev    = deg + N;                  // N*MAXD
    int*   nbr   = (int*)(ev + N * MAXD);    // N*MAXD ints
    unsigned* Wpack = (unsigned*)(nbr + N * MAXD); // 14336 u32 (16B-aligned)
    float* Wr1T  = (float*)(Wpack + WPACK_W);      // [128][64]

    init_kernel<<<1368, 256, 0, stream>>>(X, W_enc, b_enc, W_msg, b_msg,
                                          W_ih, W_hh, W_r1, A, E,
                                          h0, p0, nbr, ev, deg, Wpack, Wr1T);

    float* hc = h0; float* hn = h1;
    float* pc = p0; float* pn = p1;
    for (int s = 0; s < 3; ++s) {
        step_kernel<<<N / 8, 512, 0, stream>>>(pc, W_msg, b_msg, hc, nbr, ev, deg,
                                               Wpack, b_ih, b_hh,
                                               hn, pn, (s < 2) ? 1 : 0);
        float* t = hc; hc = hn; hn = t;
        t = pc; pc = pn; pn = t;
    }

    readout_kernel<<<1, 64, 0, stream>>>(hc, Wr1T, b_r1, W_r2, b_r2, src, tgt,
                                         (float*)d_out);
}

// Round 16
// 41.222 us; speedup vs baseline: 1.5714x; 1.1069x over previous
//
#include <hip/hip_runtime.h>
#include <math.h>

#define N 1024
#define IN_DIM 16
#define HID 64
#define MAXD 64

__device__ __forceinline__ float sigmoidf_(float x) {
    return 1.0f / (1.0f + __expf(-x));
}
// fast tanh via exp; ~1e-6 rel error, far below 1e-2 threshold
__device__ __forceinline__ float ftanh_(float x) {
    float e = __expf(2.0f * x);
    return 1.0f - 2.0f / (e + 1.0f);
}
// round-to-nearest-even fp32 -> bf16 bits
__device__ __forceinline__ unsigned rne16_(float f) {
    unsigned u = __float_as_uint(f);
    return (u + 0x7FFFu + ((u >> 16) & 1u)) >> 16;
}
__device__ __forceinline__ float blo_(unsigned u) {  // low bf16 -> float
    return __uint_as_float(u << 16);
}
__device__ __forceinline__ float bhi_(unsigned u) {  // high bf16 -> float
    return __uint_as_float(u & 0xFFFF0000u);
}

// packed weight word counts
#define WIH_W 6144   // [k2=32][row=192] two bf16 (k=2k2, 2k2+1) per word
#define WHH_W 6144
#define WMSG_W 2048  // [k2=32][j=64]
#define WPACK_W (WIH_W + WHH_W + WMSG_W)  // 14336 u32 = 56 KB

// ---- fused init (r8-proven):
//   blocks [0,256)    : encoder + proj0 (4 nodes/block)
//   blocks [256,1280) : CSR build (1 block/row)
//   blocks [1280,1368): bf16 weight packing + Wr1T transpose
__global__ void init_kernel(const float* __restrict__ X,
                            const float* __restrict__ W_enc,
                            const float* __restrict__ b_enc,
                            const float* __restrict__ W_msg,
                            const float* __restrict__ b_msg,
                            const float* __restrict__ W_ih,
                            const float* __restrict__ W_hh,
                            const float* __restrict__ W_r1,
                            const float* __restrict__ A,
                            const float* __restrict__ E,
                            float* __restrict__ h,
                            float* __restrict__ proj,
                            int* __restrict__ nbr,
                            float* __restrict__ ev,
                            float* __restrict__ deg,
                            unsigned* __restrict__ Wpack,
                            float* __restrict__ Wr1T) {
    int bid = blockIdx.x;
    int tid = threadIdx.x;
    int wave = tid >> 6;
    int lane = tid & 63;

    if (bid < 256) {
        // ---- encoder + proj0 ----
        int u = bid * 4 + wave;
        __shared__ float sh[4][HID];
        float acc = b_enc[lane];
#pragma unroll
        for (int k = 0; k < IN_DIM; ++k)
            acc += X[u * IN_DIM + k] * W_enc[lane * IN_DIM + k];
        float hv = tanhf(acc);
        h[u * HID + lane] = hv;
        sh[wave][lane] = hv;
        __syncthreads();
        float pacc = b_msg[lane];
        const float4* h4 = (const float4*)sh[wave];
#pragma unroll
        for (int k4 = 0; k4 < HID / 4; ++k4) {
            float4 hh = h4[k4];
            const float* w = &W_msg[lane * (HID + 1) + k4 * 4];
            pacc += hh.x * w[0] + hh.y * w[1] + hh.z * w[2] + hh.w * w[3];
        }
        proj[u * HID + lane] = pacc;
    } else if (bid < 1280) {
        // ---- CSR build: one 256-thread block per row u ----
        int u = bid - 256;
        __shared__ unsigned long long balls[16];
        __shared__ int base[16];
        float evr[4];
        bool has[4];
#pragma unroll
        for (int ci = 0; ci < 4; ++ci) {
            int chunk = wave * 4 + ci;
            int v = chunk * 64 + lane;
            float a = A[u * N + v];
            bool hs = (a > 0.0f);
            has[ci] = hs;
            evr[ci] = E[u * N + v];
            unsigned long long b = __ballot(hs);
            if (lane == 0) balls[chunk] = b;
        }
        __syncthreads();
        if (tid == 0) {
            int s = 0;
#pragma unroll
            for (int c = 0; c < 16; ++c) {
                base[c] = s;
                s += __popcll(balls[c]);
            }
            deg[u] = (float)s;
        }
        __syncthreads();
#pragma unroll
        for (int ci = 0; ci < 4; ++ci) {
            int chunk = wave * 4 + ci;
            if (has[ci]) {
                unsigned long long b = balls[chunk];
                int slot = base[chunk] + __popcll(b & ((1ull << lane) - 1ull));
                if (slot < MAXD) {
                    nbr[u * MAXD + slot] = chunk * 64 + lane;
                    ev[u * MAXD + slot] = evr[ci];
                }
            }
        }
    } else {
        // ---- bf16 weight packing: one u32 per thread ----
        int t = (bid - 1280) * 256 + tid;
        if (t < WIH_W) {                       // WihTp[k2*192+row]
            int k2 = t / 192, row = t % 192;
            int k = 2 * k2;
            unsigned lo = rne16_(W_ih[row * 64 + k]);
            unsigned hi = rne16_(W_ih[row * 64 + k + 1]);
            Wpack[t] = lo | (hi << 16);
        } else if (t < WIH_W + WHH_W) {        // WhhTp
            int t0 = t - WIH_W;
            int k2 = t0 / 192, row = t0 % 192;
            int k = 2 * k2;
            unsigned lo = rne16_(W_hh[row * 64 + k]);
            unsigned hi = rne16_(W_hh[row * 64 + k + 1]);
            Wpack[t] = lo | (hi << 16);
        } else if (t < WPACK_W) {              // WmsgTp[k2*64+j]
            int t0 = t - WIH_W - WHH_W;
            int k2 = t0 >> 6, j = t0 & 63;
            int k = 2 * k2;
            unsigned lo = rne16_(W_msg[j * (HID + 1) + k]);
            unsigned hi = rne16_(W_msg[j * (HID + 1) + k + 1]);
            Wpack[t] = lo | (hi << 16);
        } else if (t < WPACK_W + 8192) {       // Wr1T[k*64+j] = W_r1[j*128+k], fp32
            int t0 = t - WPACK_W;
            int j = t0 >> 7, k = t0 & 127;
            Wr1T[k * 64 + j] = W_r1[t0];
        }
    }
}

// ---- fused step (r8-proven): LDS-staged bf16 weights; gather + GRU + proj ----
__global__ void step_kernel(const float* __restrict__ proj,      // proj of h_in
                            const float* __restrict__ W_msg,     // only w_e col
                            const float* __restrict__ b_msg,
                            const float* __restrict__ hin,
                            const int* __restrict__ nbr,
                            const float* __restrict__ ev,
                            const float* __restrict__ deg,
                            const unsigned* __restrict__ Wpack,  // 14336 u32
                            const float* __restrict__ b_ih,
                            const float* __restrict__ b_hh,
                            float* __restrict__ hout,
                            float* __restrict__ projout) {
    int tid = threadIdx.x;
    int wave = tid >> 6;     // 4 waves / block, wave = node slot
    int lane = tid & 63;     // lane = hidden index
    int u = blockIdx.x * 4 + wave;

    __shared__ unsigned sw[WPACK_W];   // 56 KB packed weights
    __shared__ float sm[4][2][HID];    // [0]=msgs (later h_new), [1]=h_u

    // stage weights block-wide (uint4 = 16B chunks)
    {
        const uint4* gsrc = (const uint4*)Wpack;
        uint4* dst = (uint4*)sw;
#pragma unroll
        for (int c = 0; c < WPACK_W / 4 / 256; ++c)
            dst[c * 256 + tid] = gsrc[c * 256 + tid];
    }

    // ---- message gather (independent of sw) ----
    float we = W_msg[lane * (HID + 1) + HID];
    float d = deg[u];
    int dn = (int)d;
    float hu = hin[u * HID + lane];
    float sum = 0.0f;
    int i = 0;
    for (; i + 8 <= dn; i += 8) {
        int4 na = *(const int4*)&nbr[u * MAXD + i];
        int4 nb = *(const int4*)&nbr[u * MAXD + i + 4];
        float4 ea = *(const float4*)&ev[u * MAXD + i];
        float4 eb = *(const float4*)&ev[u * MAXD + i + 4];
        float q0 = proj[na.x * HID + lane];
        float q1 = proj[na.y * HID + lane];
        float q2 = proj[na.z * HID + lane];
        float q3 = proj[na.w * HID + lane];
        float q4 = proj[nb.x * HID + lane];
        float q5 = proj[nb.y * HID + lane];
        float q6 = proj[nb.z * HID + lane];
        float q7 = proj[nb.w * HID + lane];
        sum += ftanh_(q0 + ea.x * we) + ftanh_(q1 + ea.y * we)
             + ftanh_(q2 + ea.z * we) + ftanh_(q3 + ea.w * we);
        sum += ftanh_(q4 + eb.x * we) + ftanh_(q5 + eb.y * we)
             + ftanh_(q6 + eb.z * we) + ftanh_(q7 + eb.w * we);
    }
    for (; i + 4 <= dn; i += 4) {
        int4 nb = *(const int4*)&nbr[u * MAXD + i];
        float4 e4 = *(const float4*)&ev[u * MAXD + i];
        float q0 = proj[nb.x * HID + lane];
        float q1 = proj[nb.y * HID + lane];
        float q2 = proj[nb.z * HID + lane];
        float q3 = proj[nb.w * HID + lane];
        sum += ftanh_(q0 + e4.x * we) + ftanh_(q1 + e4.y * we)
             + ftanh_(q2 + e4.z * we) + ftanh_(q3 + e4.w * we);
    }
    for (; i < dn; ++i)
        sum += ftanh_(proj[nbr[u * MAXD + i] * HID + lane]
                      + ev[u * MAXD + i] * we);
    float msg = (dn > 0) ? (sum / d) : 0.0f;

    sm[wave][0][lane] = msg;
    sm[wave][1][lane] = hu;
    __syncthreads();   // sm ready AND sw staged

    // ---- GRU from LDS bf16 weights: lane j = output j ----
    const unsigned* swih = sw;
    const unsigned* swhh = sw + WIH_W;
    float accR  = b_ih[lane]       + b_hh[lane];
    float accZ  = b_ih[64 + lane]  + b_hh[64 + lane];
    float accNi = b_ih[128 + lane];
    float accNh = b_hh[128 + lane];
    const float2* m2 = (const float2*)sm[wave][0];
    const float2* h2 = (const float2*)sm[wave][1];
#pragma unroll
    for (int k2 = 0; k2 < 32; ++k2) {
        float2 mv = m2[k2];
        float2 hv = h2[k2];
        unsigned wiR = swih[k2 * 192 + lane];
        unsigned wiZ = swih[k2 * 192 + 64 + lane];
        unsigned wiN = swih[k2 * 192 + 128 + lane];
        unsigned whR = swhh[k2 * 192 + lane];
        unsigned whZ = swhh[k2 * 192 + 64 + lane];
        unsigned whN = swhh[k2 * 192 + 128 + lane];
        accR  += mv.x * blo_(wiR) + mv.y * bhi_(wiR)
               + hv.x * blo_(whR) + hv.y * bhi_(whR);
        accZ  += mv.x * blo_(wiZ) + mv.y * bhi_(wiZ)
               + hv.x * blo_(whZ) + hv.y * bhi_(whZ);
        accNi += mv.x * blo_(wiN) + mv.y * bhi_(wiN);
        accNh += hv.x * blo_(whN) + hv.y * bhi_(whN);
    }
    float r = sigmoidf_(accR);
    float z = sigmoidf_(accZ);
    float n = ftanh_(accNi + r * accNh);
    float hnew = (1.0f - z) * n + z * hu;
    hout[u * HID + lane] = hnew;

    // proj(h_new) for the next step's gather
    __syncthreads();             // all waves done reading sm
    sm[wave][0][lane] = hnew;
    __syncthreads();
    const unsigned* swmsg = sw + WIH_W + WHH_W;
    float pacc = b_msg[lane];
    const float2* n2 = (const float2*)sm[wave][0];
#pragma unroll
    for (int k2 = 0; k2 < 32; ++k2) {
        float2 hh = n2[k2];
        unsigned wm = swmsg[k2 * 64 + lane];
        pacc += hh.x * blo_(wm) + hh.y * bhi_(wm);
    }
    projout[u * HID + lane] = pacc;
}

// ---- lean final: 1 block x 128 (2 waves). step3 for src/tgt with weights read
//      DIRECTLY from L2-hot Wpack (no LDS staging), then readout. ----
__global__ void final_kernel(const float* __restrict__ proj,     // p2
                             const float* __restrict__ W_msg,    // only w_e col
                             const float* __restrict__ hin,      // h2
                             const int* __restrict__ nbr,
                             const float* __restrict__ ev,
                             const float* __restrict__ deg,
                             const unsigned* __restrict__ Wpack,
                             const float* __restrict__ b_ih,
                             const float* __restrict__ b_hh,
                             const float* __restrict__ Wr1T,     // [128][64]
                             const float* __restrict__ b_r1,
                             const float* __restrict__ W_r2,
                             const float* __restrict__ b_r2,
                             const int* __restrict__ src,
                             const int* __restrict__ tgt,
                             float* __restrict__ out) {
    int tid = threadIdx.x;   // 128 threads = 2 waves, both active
    int wave = tid >> 6;
    int lane = tid & 63;

    __shared__ float sm[2][2][HID];   // msgs / h per node
    __shared__ float h3s[2][HID];     // h3[src], h3[tgt]

    int u = (wave == 0) ? src[0] : tgt[0];
    float we = W_msg[lane * (HID + 1) + HID];
    float d = deg[u];
    int dn = (int)d;
    float hu = hin[u * HID + lane];
    float sum = 0.0f;
    int i = 0;
    for (; i + 4 <= dn; i += 4) {
        int4 nb = *(const int4*)&nbr[u * MAXD + i];
        float4 e4 = *(const float4*)&ev[u * MAXD + i];
        float q0 = proj[nb.x * HID + lane];
        float q1 = proj[nb.y * HID + lane];
        float q2 = proj[nb.z * HID + lane];
        float q3 = proj[nb.w * HID + lane];
        sum += ftanh_(q0 + e4.x * we) + ftanh_(q1 + e4.y * we)
             + ftanh_(q2 + e4.z * we) + ftanh_(q3 + e4.w * we);
    }
    for (; i < dn; ++i)
        sum += ftanh_(proj[nbr[u * MAXD + i] * HID + lane]
                      + ev[u * MAXD + i] * we);
    float msg = (dn > 0) ? (sum / d) : 0.0f;

    sm[wave][0][lane] = msg;
    sm[wave][1][lane] = hu;
    __syncthreads();

    // GRU with weights straight from global (L2-hot, coalesced 64-lane reads)
    const unsigned* swih = Wpack;
    const unsigned* swhh = Wpack + WIH_W;
    float accR  = b_ih[lane]       + b_hh[lane];
    float accZ  = b_ih[64 + lane]  + b_hh[64 + lane];
    float accNi = b_ih[128 + lane];
    float accNh = b_hh[128 + lane];
    const float2* m2 = (const float2*)sm[wave][0];
    const float2* h2 = (const float2*)sm[wave][1];
#pragma unroll
    for (int k2 = 0; k2 < 32; ++k2) {
        float2 mv = m2[k2];
        float2 hv = h2[k2];
        unsigned wiR = swih[k2 * 192 + lane];
        unsigned wiZ = swih[k2 * 192 + 64 + lane];
        unsigned wiN = swih[k2 * 192 + 128 + lane];
        unsigned whR = swhh[k2 * 192 + lane];
        unsigned whZ = swhh[k2 * 192 + 64 + lane];
        unsigned whN = swhh[k2 * 192 + 128 + lane];
        accR  += mv.x * blo_(wiR) + mv.y * bhi_(wiR)
               + hv.x * blo_(whR) + hv.y * bhi_(whR);
        accZ  += mv.x * blo_(wiZ) + mv.y * bhi_(wiZ)
               + hv.x * blo_(whZ) + hv.y * bhi_(whZ);
        accNi += mv.x * blo_(wiN) + mv.y * bhi_(wiN);
        accNh += hv.x * blo_(whN) + hv.y * bhi_(whN);
    }
    float r = sigmoidf_(accR);
    float z = sigmoidf_(accZ);
    float n = ftanh_(accNi + r * accNh);
    h3s[wave][lane] = (1.0f - z) * n + z * hu;
    __syncthreads();

    // ---- readout (wave 0) ----
    if (wave == 0) {
        float acc = b_r1[lane];
#pragma unroll 8
        for (int k = 0; k < HID; ++k)
            acc += h3s[0][k] * Wr1T[k * 64 + lane];
#pragma unroll 8
        for (int k = 0; k < HID; ++k)
            acc += h3s[1][k] * Wr1T[(HID + k) * 64 + lane];
        float hid = fmaxf(acc, 0.0f);
        float p = hid * W_r2[lane];
#pragma unroll
        for (int off = 32; off > 0; off >>= 1)
            p += __shfl_down(p, off);
        if (lane == 0) out[0] = sigmoidf_(p + b_r2[0]);
    }
}

extern "C" void kernel_launch(void* const* d_in, const int* in_sizes, int n_in,
                              void* d_out, int out_size, void* d_ws, size_t ws_size,
                              hipStream_t stream) {
    const float* A     = (const float*)d_in[0];
    const float* E     = (const float*)d_in[1];
    const float* X     = (const float*)d_in[2];
    const float* W_enc = (const float*)d_in[3];
    const float* b_enc = (const float*)d_in[4];
    const float* W_msg = (const float*)d_in[5];
    const float* b_msg = (const float*)d_in[6];
    const float* W_ih  = (const float*)d_in[7];
    const float* W_hh  = (const float*)d_in[8];
    const float* b_ih  = (const float*)d_in[9];
    const float* b_hh  = (const float*)d_in[10];
    const float* W_r1  = (const float*)d_in[11];
    const float* b_r1  = (const float*)d_in[12];
    const float* W_r2  = (const float*)d_in[13];
    const float* b_r2  = (const float*)d_in[14];
    const int*   src   = (const int*)d_in[15];
    const int*   tgt   = (const int*)d_in[16];
    // steps fixed at 3 in the reference: 2 wide step kernels + lean final.

    // workspace layout
    float* ws    = (float*)d_ws;
    float* h0    = ws;                       // N*HID
    float* h1    = h0 + N * HID;             // N*HID
    float* p0    = h1 + N * HID;             // N*HID
    float* p1    = p0 + N * HID;             // N*HID
    float* deg   = p1 + N * HID;             // N
    float* ev    = deg + N;                  // N*MAXD
    int*   nbr   = (int*)(ev + N * MAXD);    // N*MAXD ints
    unsigned* Wpack = (unsigned*)(nbr + N * MAXD); // 14336 u32 (16B-aligned)
    float* Wr1T  = (float*)(Wpack + WPACK_W);      // [128][64]

    init_kernel<<<1368, 256, 0, stream>>>(X, W_enc, b_enc, W_msg, b_msg,
                                          W_ih, W_hh, W_r1, A, E,
                                          h0, p0, nbr, ev, deg, Wpack, Wr1T);

    // step 1: h0,p0 -> h1,p1 ; step 2: h1,p1 -> h0,p0 (= h2,p2)
    step_kernel<<<N / 4, 256, 0, stream>>>(p0, W_msg, b_msg, h0, nbr, ev, deg,
                                           Wpack, b_ih, b_hh, h1, p1);
    step_kernel<<<N / 4, 256, 0, stream>>>(p1, W_msg, b_msg, h1, nbr, ev, deg,
                                           Wpack, b_ih, b_hh, h0, p0);

    // final: step3(src,tgt) + readout
    final_kernel<<<1, 128, 0, stream>>>(p0, W_msg, h0, nbr, ev, deg,
                                        Wpack, b_ih, b_hh,
                                        Wr1T, b_r1, W_r2, b_r2, src, tgt,
                                        (float*)d_out);
}